// Round 1
// baseline (1026.675 us; speedup 1.0000x reference)
//
#include <hip/hip_runtime.h>
#include <math.h>

#define B_   32
#define NCq  62
#define F_   256
#define NE   512
#define M_   (B_*NCq)      // 1984
#define NCOL (NCq*F_)      // 15872
#define NZ   (M_*NCq)      // 123008
#define EPSF 1e-6f

__device__ __forceinline__ float eluf(float x){ return x > 0.0f ? x : expm1f(x); }

// ---------------- prep: codebook transpose, norms, output copy ----------------
__global__ __launch_bounds__(256) void k_prep(const float* __restrict__ cb, float* __restrict__ ct,
                                              float* __restrict__ cnorm, float* __restrict__ out_cb){
    int e = blockIdx.x; int d = threadIdx.x;
    float v = cb[e*F_ + d];
    out_cb[e*F_ + d] = v;
    ct[d*NE + e] = v;
    float s = v*v;
    #pragma unroll
    for(int m=32;m;m>>=1) s += __shfl_xor(s, m, 64);
    __shared__ float red[4];
    if((threadIdx.x & 63)==0) red[threadIdx.x>>6] = s;
    __syncthreads();
    if(threadIdx.x==0) cnorm[e] = red[0]+red[1]+red[2]+red[3];
}

// ---------------- o = p @ x + bias ----------------
__global__ __launch_bounds__(256) void k_o(const float* __restrict__ x, const float* __restrict__ p,
                                           const float* __restrict__ bias, float* __restrict__ o){
    int bi = blockIdx.x; int d = threadIdx.x;
    int b = bi / NCq, i = bi % NCq;
    __shared__ float pr[NCq];
    if(d < NCq) pr[d] = p[i*NCq + d];
    __syncthreads();
    float acc = bias[i*F_ + d];
    const float* xb = x + (size_t)b*NCq*F_ + d;
    #pragma unroll 2
    for(int j=0;j<NCq;j++) acc = fmaf(pr[j], xb[j*F_], acc);
    o[bi*F_ + d] = acc;
}

// ---------------- t = o @ q ----------------
__global__ __launch_bounds__(256) void k_t(const float* __restrict__ o, const float* __restrict__ q,
                                           float* __restrict__ t){
    int bi = blockIdx.x; int e = threadIdx.x;
    __shared__ float orow[F_];
    orow[e] = o[bi*F_ + e];
    __syncthreads();
    float acc = 0.f;
    #pragma unroll 4
    for(int d=0; d<F_; d++) acc = fmaf(orow[d], q[d*F_ + e], acc);
    t[bi*F_ + e] = acc;
}

// ---------------- G = ELU(t @ theta)  [1984 x 15872] ----------------
// tiles: BM=64, BN=64, BK=32; 256 threads, 4x4 per thread
__global__ __launch_bounds__(256) void k_gemm_g(const float* __restrict__ T, const float* __restrict__ TH,
                                                float* __restrict__ G){
    __shared__ float As[32][68];   // [k][m] (transposed), pad keeps 16B align
    __shared__ float Bs[32][64];   // [k][n]
    int tid = threadIdx.x;
    int row0 = blockIdx.x * 64;
    int col0 = blockIdx.y * 64;
    int tx = tid & 15, ty = tid >> 4;
    float acc[4][4] = {};
    int ka = tid & 31, ra = tid >> 5;
    int nb = tid & 63, kb = tid >> 6;
    for(int kc=0; kc<F_; kc+=32){
        #pragma unroll
        for(int p2=0;p2<8;p2++){
            int r = ra + p2*8;
            As[ka][r] = T[(row0 + r)*F_ + kc + ka];
        }
        #pragma unroll
        for(int p2=0;p2<8;p2++){
            int k = kb + p2*4;
            Bs[k][nb] = TH[(size_t)(kc + k)*NCOL + col0 + nb];
        }
        __syncthreads();
        #pragma unroll
        for(int k=0;k<32;k++){
            float a4[4], b4[4];
            *(float4*)a4 = *(const float4*)&As[k][ty*4];
            *(float4*)b4 = *(const float4*)&Bs[k][tx*4];
            #pragma unroll
            for(int r=0;r<4;r++)
                #pragma unroll
                for(int c=0;c<4;c++) acc[r][c] = fmaf(a4[r], b4[c], acc[r][c]);
        }
        __syncthreads();
    }
    #pragma unroll
    for(int r=0;r<4;r++){
        float4 v;
        v.x = eluf(acc[r][0]); v.y = eluf(acc[r][1]);
        v.z = eluf(acc[r][2]); v.w = eluf(acc[r][3]);
        *(float4*)&G[(size_t)(row0 + ty*4 + r)*NCOL + col0 + tx*4] = v;
    }
}

// ---------------- inv_den[bi,d] = 1/(sum_j |G[bi, j*256+d]| + eps) ----------------
__global__ __launch_bounds__(256) void k_den(const float* __restrict__ G, float* __restrict__ inv_den){
    int bi = blockIdx.x; int d = threadIdx.x;
    const float* g = G + (size_t)bi*NCOL + d;
    float s = 0.f;
    #pragma unroll 2
    for(int j=0;j<NCq;j++) s += fabsf(g[j*F_]);
    inv_den[bi*F_ + d] = 1.0f / (s + EPSF);
}

// ---------------- znorm[n] = sum_d z^2 ----------------
__global__ __launch_bounds__(256) void k_znorm(const float* __restrict__ G, const float* __restrict__ inv_den,
                                               float* __restrict__ znorm){
    int wv = threadIdx.x >> 6, lane = threadIdx.x & 63;
    int n = blockIdx.x*4 + wv;
    int bi = n / NCq;
    float4 g = *(const float4*)&G[(size_t)n*F_ + lane*4];
    float4 iv = *(const float4*)&inv_den[bi*F_ + lane*4];
    float zx=g.x*iv.x, zy=g.y*iv.y, zz=g.z*iv.z, zw=g.w*iv.w;
    float s = zx*zx+zy*zy+zz*zz+zw*zw;
    #pragma unroll
    for(int m=32;m;m>>=1) s += __shfl_xor(s,m,64);
    if(lane==0) znorm[n]=s;
}

// ---------------- VQ GEMM + partial argmin: tile 64 rows x 128 codes ----------------
__global__ __launch_bounds__(256) void k_vq(const float* __restrict__ G, const float* __restrict__ inv_den,
                                            const float* __restrict__ CT, const float* __restrict__ cnorm,
                                            float* __restrict__ pmin, int* __restrict__ pidx){
    __shared__ float As[32][68];    // [k][m]
    __shared__ float Bs[32][128];   // [k][n]
    int tid = threadIdx.x;
    int n0 = blockIdx.x * 64;
    int cbk = blockIdx.y;
    int col0 = cbk * 128;
    int tx = tid & 31, ty = tid >> 5;
    float acc[8][4] = {};
    int ka = tid & 31, ra = tid >> 5;
    int nb = tid & 127, kb = tid >> 7;
    for(int kc=0; kc<F_; kc+=32){
        #pragma unroll
        for(int p2=0;p2<8;p2++){
            int r = ra + p2*8;
            int n = n0 + r;
            int bi = n / NCq;
            As[ka][r] = G[(size_t)n*F_ + kc + ka] * inv_den[bi*F_ + kc + ka];
        }
        #pragma unroll
        for(int p2=0;p2<16;p2++){
            int k = kb + p2*2;
            Bs[k][nb] = CT[(kc + k)*NE + col0 + nb];
        }
        __syncthreads();
        #pragma unroll
        for(int k=0;k<32;k++){
            float a8[8], b4[4];
            *(float4*)&a8[0] = *(const float4*)&As[k][ty*8];
            *(float4*)&a8[4] = *(const float4*)&As[k][ty*8+4];
            *(float4*)b4 = *(const float4*)&Bs[k][tx*4];
            #pragma unroll
            for(int r=0;r<8;r++)
                #pragma unroll
                for(int c=0;c<4;c++) acc[r][c] = fmaf(a8[r], b4[c], acc[r][c]);
        }
        __syncthreads();
    }
    // epilogue: score = cnorm - 2*dot; per-row argmin over this 128-code block
    float4 cn = *(const float4*)&cnorm[col0 + tx*4];
    #pragma unroll
    for(int rr=0;rr<8;rr++){
        float v0 = cn.x - 2.f*acc[rr][0];
        float v1 = cn.y - 2.f*acc[rr][1];
        float v2 = cn.z - 2.f*acc[rr][2];
        float v3 = cn.w - 2.f*acc[rr][3];
        int base = col0 + tx*4;
        float bv = v0; int bidx = base;
        if(v1 < bv){bv=v1;bidx=base+1;}
        if(v2 < bv){bv=v2;bidx=base+2;}
        if(v3 < bv){bv=v3;bidx=base+3;}
        #pragma unroll
        for(int m2=16;m2;m2>>=1){
            float ov = __shfl_xor(bv, m2, 32);
            int   oi = __shfl_xor(bidx, m2, 32);
            if(ov < bv || (ov==bv && oi < bidx)){ bv=ov; bidx=oi; }
        }
        if(tx==0){
            int n = n0 + ty*8 + rr;
            pmin[n*4 + cbk] = bv;
            pidx[n*4 + cbk] = bidx;
        }
    }
}

// ---------------- finalize: min over 4 blocks, histograms, loss ----------------
__global__ __launch_bounds__(128) void k_fin(const float* __restrict__ pmin, const int* __restrict__ pidx,
                                             const float* __restrict__ znorm, int* __restrict__ idx,
                                             int* __restrict__ counts, int* __restrict__ countb,
                                             double* __restrict__ loss_sum){
    int n = blockIdx.x*128 + threadIdx.x;
    float bv = pmin[n*4]; int bix = pidx[n*4];
    #pragma unroll
    for(int c=1;c<4;c++){
        float v = pmin[n*4+c]; int i2 = pidx[n*4+c];
        if(v < bv || (v==bv && i2<bix)){ bv=v; bix=i2; }
    }
    idx[n] = bix;
    atomicAdd(&counts[bix], 1);
    int b = n / (NCq*NCq);
    atomicAdd(&countb[b*NE + bix], 1);
    float md = znorm[n] + bv;
    #pragma unroll
    for(int m=32;m;m>>=1) md += __shfl_xor(md, m, 64);
    __shared__ float red[2];
    if((threadIdx.x&63)==0) red[threadIdx.x>>6] = md;
    __syncthreads();
    if(threadIdx.x==0) atomicAdd(loss_sum, (double)(red[0]+red[1]));
}

// ---------------- scalars: vq_loss and usage ----------------
__global__ __launch_bounds__(256) void k_scal(const int* __restrict__ counts, const double* __restrict__ loss_sum,
                                              float* __restrict__ out){
    int t = threadIdx.x;
    float ent = 0.f;
    for(int e=t; e<NE; e+=256){
        float pr = (float)counts[e] / (float)NZ;
        ent += pr * logf(pr + 1e-10f);
    }
    #pragma unroll
    for(int m=32;m;m>>=1) ent += __shfl_xor(ent,m,64);
    __shared__ float red[4];
    if((t&63)==0) red[t>>6]=ent;
    __syncthreads();
    if(t==0){
        float e2 = red[0]+red[1]+red[2]+red[3];
        out[1+NZ] = expf(-e2);
        out[0] = (float)(1.25 * (*loss_sum) / ((double)NZ * (double)F_));
    }
}

// ---------------- SE block: s2p1 = 1 + sigmoid(MLP(mean)) per (b,d) ----------------
__global__ __launch_bounds__(256) void k_se(const int* __restrict__ countb, const float* __restrict__ cb,
                                            const float* __restrict__ w1, const float* __restrict__ b1,
                                            const float* __restrict__ w2, const float* __restrict__ b2,
                                            float* __restrict__ s2p1){
    int b = blockIdx.x; int d = threadIdx.x;
    __shared__ float cnt[NE];
    __shared__ float s_sh[F_];
    __shared__ float h_sh[16];
    cnt[d]       = (float)countb[b*NE + d];
    cnt[d + 256] = (float)countb[b*NE + d + 256];
    __syncthreads();
    float s = 0.f;
    for(int e=0;e<NE;e++) s = fmaf(cnt[e], cb[e*F_ + d], s);
    s *= (1.0f/(float)(NCq*NCq));
    s_sh[d] = s;
    __syncthreads();
    if(d < 16){
        float h = b1[d];
        for(int k=0;k<F_;k++) h = fmaf(s_sh[k], w1[k*16 + d], h);
        h_sh[d] = fmaxf(h, 0.f);
    }
    __syncthreads();
    float v = b2[d];
    #pragma unroll
    for(int r=0;r<16;r++) v = fmaf(h_sh[r], w2[r*F_ + d], v);
    s2p1[b*F_ + d] = 1.0f + 1.0f/(1.0f + expf(-v));
}

// ---------------- w[b,e] = sum_d elu(c[e,d]*(1+s2[b,d])) ----------------
__global__ __launch_bounds__(256) void k_w(const float* __restrict__ cb, const float* __restrict__ s2p1,
                                           float* __restrict__ wtab){
    int b = blockIdx.x; int eg = blockIdx.y;
    int wv = threadIdx.x>>6, lane = threadIdx.x&63;
    __shared__ float m_sh[F_];
    m_sh[threadIdx.x] = s2p1[b*F_ + threadIdx.x];
    __syncthreads();
    int e = eg*4 + wv;
    float4 c4 = *(const float4*)&cb[e*F_ + lane*4];
    float s = eluf(c4.x*m_sh[lane*4]) + eluf(c4.y*m_sh[lane*4+1])
            + eluf(c4.z*m_sh[lane*4+2]) + eluf(c4.w*m_sh[lane*4+3]);
    #pragma unroll
    for(int m2=32;m2;m2>>=1) s += __shfl_xor(s,m2,64);
    if(lane==0) wtab[b*NE + e] = s;
}

// ---------------- final: out[b,i,j] = normalize_j(elu(w[b, idx])) ----------------
__global__ __launch_bounds__(64) void k_out(const int* __restrict__ idx, const float* __restrict__ wtab,
                                            float* __restrict__ out){
    int bi = blockIdx.x; int j = threadIdx.x;
    int b = bi / NCq;
    float v = 0.f;
    if(j < NCq) v = eluf(wtab[b*NE + idx[bi*NCq + j]]);
    float a = fabsf(v);
    #pragma unroll
    for(int m=32;m;m>>=1) a += __shfl_xor(a,m,64);
    if(j < NCq) out[1 + bi*NCq + j] = v / (a + EPSF);
}

extern "C" void kernel_launch(void* const* d_in, const int* in_sizes, int n_in,
                              void* d_out, int out_size, void* d_ws, size_t ws_size,
                              hipStream_t stream){
    (void)in_sizes; (void)n_in; (void)out_size; (void)ws_size;
    const float* x    = (const float*)d_in[0];
    const float* p    = (const float*)d_in[1];
    const float* bias = (const float*)d_in[2];
    const float* q    = (const float*)d_in[3];
    const float* th   = (const float*)d_in[4];
    const float* cb   = (const float*)d_in[5];
    const float* w1   = (const float*)d_in[6];
    const float* b1   = (const float*)d_in[7];
    const float* w2   = (const float*)d_in[8];
    const float* b2   = (const float*)d_in[9];
    float* out = (float*)d_out;
    char* ws = (char*)d_ws;
    size_t off = 0;
    auto alloc = [&](size_t bytes){ void* ptr = ws + off; off = (off + bytes + 255) & ~255ull; return ptr; };
    float* G    = (float*)alloc((size_t)M_*NCOL*sizeof(float));   // 126 MB
    float* O    = (float*)alloc((size_t)M_*F_*sizeof(float));
    float* T    = (float*)alloc((size_t)M_*F_*sizeof(float));
    float* INV  = (float*)alloc((size_t)M_*F_*sizeof(float));
    float* CT   = (float*)alloc((size_t)NE*F_*sizeof(float));
    float* CN   = (float*)alloc((size_t)NE*sizeof(float));
    float* ZN   = (float*)alloc((size_t)NZ*sizeof(float));
    float* PMIN = (float*)alloc((size_t)NZ*4*sizeof(float));
    int*   PIDX = (int*)  alloc((size_t)NZ*4*sizeof(int));
    int*   IDX  = (int*)  alloc((size_t)NZ*sizeof(int));
    char*  zbase= (char*) alloc(8 + NE*sizeof(int) + (size_t)B_*NE*sizeof(int));
    double* LOSS   = (double*)zbase;
    int*    COUNTS = (int*)(zbase + 8);
    int*    COUNTB = (int*)(zbase + 8 + NE*sizeof(int));
    float* S2P1 = (float*)alloc((size_t)B_*F_*sizeof(float));
    float* WTAB = (float*)alloc((size_t)B_*NE*sizeof(float));

    hipMemsetAsync(zbase, 0, 8 + NE*sizeof(int) + (size_t)B_*NE*sizeof(int), stream);
    k_prep<<<NE, 256, 0, stream>>>(cb, CT, CN, out + 1 + NZ + 1);
    k_o<<<M_, 256, 0, stream>>>(x, p, bias, O);
    k_t<<<M_, 256, 0, stream>>>(O, q, T);
    dim3 g3(M_/64, NCOL/64);
    k_gemm_g<<<g3, 256, 0, stream>>>(T, th, G);
    k_den<<<M_, 256, 0, stream>>>(G, INV);
    k_znorm<<<NZ/4, 256, 0, stream>>>(G, INV, ZN);
    dim3 g5(NZ/64, 4);
    k_vq<<<g5, 256, 0, stream>>>(G, INV, CT, CN, PMIN, PIDX);
    k_fin<<<NZ/128, 128, 0, stream>>>(PMIN, PIDX, ZN, IDX, COUNTS, COUNTB, LOSS);
    k_scal<<<1, 256, 0, stream>>>(COUNTS, LOSS, out);
    k_se<<<B_, 256, 0, stream>>>(COUNTB, cb, w1, b1, w2, b2, S2P1);
    dim3 g8(B_, NE/4);
    k_w<<<g8, 256, 0, stream>>>(cb, S2P1, WTAB);
    k_out<<<M_, 64, 0, stream>>>(IDX, WTAB, out);
}

// Round 3
// 616.096 us; speedup vs baseline: 1.6664x; 1.6664x over previous
//
#include <hip/hip_runtime.h>
#include <math.h>

#define B_   32
#define NCq  62
#define F_   256
#define NE   512
#define M_   (B_*NCq)      // 1984
#define NCOL (NCq*F_)      // 15872
#define NZ   (M_*NCq)      // 123008
#define EPSF 1e-6f

typedef unsigned short ushort_t;
typedef unsigned int uint_t;
typedef __bf16 bf8_t __attribute__((ext_vector_type(8)));
typedef float f4_t __attribute__((ext_vector_type(4)));
typedef ushort_t us8_t __attribute__((ext_vector_type(8)));
typedef ushort_t us4_t __attribute__((ext_vector_type(4)));

__device__ __forceinline__ float eluf(float x){ return x > 0.0f ? x : expm1f(x); }

__device__ __forceinline__ ushort_t bf16_rne(float f){
    uint_t u = __float_as_uint(f);
    uint_t r = (u + 0x7FFFu + ((u >> 16) & 1u)) >> 16;
    return (ushort_t)r;
}
__device__ __forceinline__ float bf16_f(ushort_t h){ return __uint_as_float(((uint_t)h) << 16); }
// returns lo<<16 | hi packed
__device__ __forceinline__ uint_t split2p(float f){
    ushort_t h = bf16_rne(f);
    ushort_t l = bf16_rne(f - bf16_f(h));
    return ((uint_t)l << 16) | (uint_t)h;
}

// ---------------- split theta, transposed: THt[n][k] = TH[k][n] ----------------
__global__ __launch_bounds__(256) void k_split_th(const float* __restrict__ TH,
                                                  ushort_t* __restrict__ THh, ushort_t* __restrict__ THl){
    __shared__ float tile[32][33];
    int n0 = blockIdx.x * 32, k0 = blockIdx.y * 32;
    int tid = threadIdx.x;
    int cc = tid & 31, rr = tid >> 5;
    #pragma unroll
    for(int p=0;p<4;p++){
        int kk = rr + p*8;
        tile[kk][cc] = TH[(size_t)(k0+kk)*NCOL + n0 + cc];
    }
    __syncthreads();
    #pragma unroll
    for(int p=0;p<4;p++){
        int nn = rr + p*8;
        uint_t pk = split2p(tile[cc][nn]);
        size_t o = (size_t)(n0+nn)*F_ + k0 + cc;
        THh[o] = (ushort_t)(pk & 0xFFFFu);
        THl[o] = (ushort_t)(pk >> 16);
    }
}

// ---------------- codebook: split hi/lo, norms, output copy ----------------
__global__ __launch_bounds__(256) void k_prep(const float* __restrict__ cb,
                                              ushort_t* __restrict__ CBh, ushort_t* __restrict__ CBl,
                                              float* __restrict__ cnorm, float* __restrict__ out_cb){
    int e = blockIdx.x; int d = threadIdx.x;
    float v = cb[e*F_ + d];
    out_cb[e*F_ + d] = v;
    uint_t pk = split2p(v);
    CBh[e*F_ + d] = (ushort_t)(pk & 0xFFFFu);
    CBl[e*F_ + d] = (ushort_t)(pk >> 16);
    float s = v*v;
    #pragma unroll
    for(int m=32;m;m>>=1) s += __shfl_xor(s, m, 64);
    __shared__ float red[4];
    if((threadIdx.x & 63)==0) red[threadIdx.x>>6] = s;
    __syncthreads();
    if(threadIdx.x==0) cnorm[e] = red[0]+red[1]+red[2]+red[3];
}

// ---------------- o = p@x+bias; t = o@q; write split t ----------------
__global__ __launch_bounds__(256) void k_ot(const float* __restrict__ x, const float* __restrict__ p,
                                            const float* __restrict__ bias, const float* __restrict__ q,
                                            ushort_t* __restrict__ Th, ushort_t* __restrict__ Tl){
    int bi = blockIdx.x; int d = threadIdx.x;
    int b = bi / NCq, i = bi % NCq;
    __shared__ float pr[NCq];
    __shared__ float orow[F_];
    if(d < NCq) pr[d] = p[i*NCq + d];
    __syncthreads();
    float acc = bias[i*F_ + d];
    const float* xb = x + (size_t)b*NCq*F_ + d;
    #pragma unroll 2
    for(int j=0;j<NCq;j++) acc = fmaf(pr[j], xb[j*F_], acc);
    orow[d] = acc;
    __syncthreads();
    float t = 0.f;
    #pragma unroll 4
    for(int k=0;k<F_;k++) t = fmaf(orow[k], q[k*F_ + d], t);
    uint_t pk = split2p(t);
    Th[bi*F_ + d] = (ushort_t)(pk & 0xFFFFu);
    Tl[bi*F_ + d] = (ushort_t)(pk >> 16);
}

// ---------------- G = ELU(T @ theta) via split-bf16 MFMA ----------------
// block tile 64m x 128n, K-chunk 32, 4 waves in 2x2
__global__ __launch_bounds__(256) void k_gemm_g(const ushort_t* __restrict__ Th, const ushort_t* __restrict__ Tl,
                                                const ushort_t* __restrict__ Bht, const ushort_t* __restrict__ Blt,
                                                float* __restrict__ G){
    __shared__ ushort_t Ah[64*40], Al[64*40], Bh[128*40], Bl[128*40];
    int tid = threadIdx.x;
    int l = tid & 63, w = tid >> 6;
    int wr = w >> 1, wc = w & 1;
    int m = l & 15, quad = l >> 4;
    int row0 = blockIdx.x * 64, col0 = blockIdx.y * 128;
    f4_t acc[2][4] = {};
    int srow = tid >> 2, spiece = tid & 3;
    for(int kc=0; kc<F_; kc+=32){
        {   size_t go = (size_t)(row0 + srow)*F_ + kc + spiece*8;
            int lo_ = srow*40 + spiece*8;
            *(us8_t*)&Ah[lo_] = *(const us8_t*)&Th[go];
            *(us8_t*)&Al[lo_] = *(const us8_t*)&Tl[go];
        }
        #pragma unroll
        for(int p2=0;p2<2;p2++){
            int idx = tid + p2*256;
            int row = idx >> 2, piece = idx & 3;
            size_t go = (size_t)(col0 + row)*F_ + kc + piece*8;
            int lo_ = row*40 + piece*8;
            *(us8_t*)&Bh[lo_] = *(const us8_t*)&Bht[go];
            *(us8_t*)&Bl[lo_] = *(const us8_t*)&Blt[go];
        }
        __syncthreads();
        bf8_t a_h[2], a_l[2];
        #pragma unroll
        for(int mt=0;mt<2;mt++){
            int off = (wr*32 + mt*16 + m)*40 + quad*8;
            a_h[mt] = *(const bf8_t*)&Ah[off];
            a_l[mt] = *(const bf8_t*)&Al[off];
        }
        #pragma unroll
        for(int nt=0;nt<4;nt++){
            int off = (wc*64 + nt*16 + m)*40 + quad*8;
            bf8_t b_h = *(const bf8_t*)&Bh[off];
            bf8_t b_l = *(const bf8_t*)&Bl[off];
            #pragma unroll
            for(int mt=0;mt<2;mt++){
                acc[mt][nt] = __builtin_amdgcn_mfma_f32_16x16x32_bf16(a_h[mt], b_h, acc[mt][nt], 0,0,0);
                acc[mt][nt] = __builtin_amdgcn_mfma_f32_16x16x32_bf16(a_h[mt], b_l, acc[mt][nt], 0,0,0);
                acc[mt][nt] = __builtin_amdgcn_mfma_f32_16x16x32_bf16(a_l[mt], b_h, acc[mt][nt], 0,0,0);
            }
        }
        __syncthreads();
    }
    #pragma unroll
    for(int mt=0;mt<2;mt++){
        #pragma unroll
        for(int nt=0;nt<4;nt++){
            int rowb = row0 + wr*32 + mt*16 + quad*4;
            int colb = col0 + wc*64 + nt*16 + m;
            #pragma unroll
            for(int r=0;r<4;r++)
                G[(size_t)(rowb + r)*NCOL + colb] = eluf(acc[mt][nt][r]);
        }
    }
}

// ---------------- inv_den + total sum of z^2 (for loss) ----------------
__global__ __launch_bounds__(256) void k_den(const float* __restrict__ G, float* __restrict__ inv_den,
                                             double* __restrict__ loss_sum){
    int bi = blockIdx.x; int d = threadIdx.x;
    const float* g = G + (size_t)bi*NCOL + d;
    float s1 = 0.f, s2 = 0.f;
    #pragma unroll 2
    for(int j=0;j<NCq;j++){ float v = g[j*F_]; s1 += fabsf(v); s2 = fmaf(v, v, s2); }
    float inv = 1.0f / (s1 + EPSF);
    inv_den[bi*F_ + d] = inv;
    float c = s2 * inv * inv;
    #pragma unroll
    for(int m=32;m;m>>=1) c += __shfl_xor(c, m, 64);
    __shared__ float red[4];
    if((threadIdx.x&63)==0) red[threadIdx.x>>6] = c;
    __syncthreads();
    if(threadIdx.x==0) atomicAdd(loss_sum, (double)(red[0]+red[1]+red[2]+red[3]));
}

// ---------------- VQ: dist GEMM (split-bf16 MFMA) + per-half argmin ----------------
// block: 128 rows x 256 codes; 4 waves, each 32 rows x 256 codes
__global__ __launch_bounds__(256,2) void k_vq(const float* __restrict__ G, const float* __restrict__ inv_den,
                                              const ushort_t* __restrict__ CBh, const ushort_t* __restrict__ CBl,
                                              const float* __restrict__ cnorm,
                                              float* __restrict__ pmin, int* __restrict__ pidx){
    __shared__ ushort_t Ah[128*40], Al[128*40], Bh[256*40], Bl[256*40];  // 60 KB
    int tid = threadIdx.x;
    int l = tid & 63, w = tid >> 6;
    int m = l & 15, quad = l >> 4;
    int n_base = blockIdx.x * 128;
    int e0 = blockIdx.y * 256;
    f4_t acc[2][16] = {};
    for(int kc=0; kc<F_; kc+=32){
        #pragma unroll
        for(int p2=0;p2<4;p2++){
            int idx = tid + p2*256;
            int row = idx >> 3, piece = idx & 7;
            int n = n_base + row;
            int bi = n / NCq;
            float4 g = *(const float4*)&G[(size_t)n*F_ + kc + piece*4];
            float4 iv = *(const float4*)&inv_den[bi*F_ + kc + piece*4];
            uint_t p0 = split2p(g.x*iv.x);
            uint_t p1 = split2p(g.y*iv.y);
            uint_t p2k = split2p(g.z*iv.z);
            uint_t p3 = split2p(g.w*iv.w);
            us4_t h4, l4;
            h4[0]=(ushort_t)(p0&0xFFFFu); l4[0]=(ushort_t)(p0>>16);
            h4[1]=(ushort_t)(p1&0xFFFFu); l4[1]=(ushort_t)(p1>>16);
            h4[2]=(ushort_t)(p2k&0xFFFFu); l4[2]=(ushort_t)(p2k>>16);
            h4[3]=(ushort_t)(p3&0xFFFFu); l4[3]=(ushort_t)(p3>>16);
            int lo_ = row*40 + piece*4;
            *(us4_t*)&Ah[lo_] = h4;
            *(us4_t*)&Al[lo_] = l4;
        }
        #pragma unroll
        for(int p2=0;p2<4;p2++){
            int idx = tid + p2*256;
            int row = idx >> 2, piece = idx & 3;
            size_t go = (size_t)(e0 + row)*F_ + kc + piece*8;
            int lo_ = row*40 + piece*8;
            *(us8_t*)&Bh[lo_] = *(const us8_t*)&CBh[go];
            *(us8_t*)&Bl[lo_] = *(const us8_t*)&CBl[go];
        }
        __syncthreads();
        bf8_t a_h[2], a_l[2];
        #pragma unroll
        for(int mt=0;mt<2;mt++){
            int off = (w*32 + mt*16 + m)*40 + quad*8;
            a_h[mt] = *(const bf8_t*)&Ah[off];
            a_l[mt] = *(const bf8_t*)&Al[off];
        }
        #pragma unroll
        for(int nt=0;nt<16;nt++){
            int off = (nt*16 + m)*40 + quad*8;
            bf8_t b_h = *(const bf8_t*)&Bh[off];
            bf8_t b_l = *(const bf8_t*)&Bl[off];
            #pragma unroll
            for(int mt=0;mt<2;mt++){
                acc[mt][nt] = __builtin_amdgcn_mfma_f32_16x16x32_bf16(a_h[mt], b_h, acc[mt][nt], 0,0,0);
                acc[mt][nt] = __builtin_amdgcn_mfma_f32_16x16x32_bf16(a_h[mt], b_l, acc[mt][nt], 0,0,0);
                acc[mt][nt] = __builtin_amdgcn_mfma_f32_16x16x32_bf16(a_l[mt], b_h, acc[mt][nt], 0,0,0);
            }
        }
        __syncthreads();
    }
    // epilogue: score = cnorm - 2*dot; argmin over the 256 codes of this half
    float bv[2][4]; int bix[2][4];
    #pragma unroll
    for(int mt=0;mt<2;mt++)
        #pragma unroll
        for(int r=0;r<4;r++){ bv[mt][r] = 3.4e38f; bix[mt][r] = 0; }
    #pragma unroll
    for(int nt=0;nt<16;nt++){
        float cn = cnorm[e0 + nt*16 + m];
        int e = e0 + nt*16 + m;
        #pragma unroll
        for(int mt=0;mt<2;mt++){
            #pragma unroll
            for(int r=0;r<4;r++){
                float v = cn - 2.0f*acc[mt][nt][r];
                if(v < bv[mt][r]){ bv[mt][r] = v; bix[mt][r] = e; }
            }
        }
    }
    #pragma unroll
    for(int mt=0;mt<2;mt++){
        #pragma unroll
        for(int r=0;r<4;r++){
            float v = bv[mt][r]; int ix = bix[mt][r];
            #pragma unroll
            for(int mk=8;mk;mk>>=1){
                float ov = __shfl_xor(v, mk, 64);
                int   oi = __shfl_xor(ix, mk, 64);
                if(ov < v || (ov == v && oi < ix)){ v = ov; ix = oi; }
            }
            if(m == 0){
                int n = n_base + w*32 + mt*16 + quad*4 + r;
                pmin[n*2 + blockIdx.y] = v;
                pidx[n*2 + blockIdx.y] = ix;
            }
        }
    }
}

// ---------------- finalize: min over halves, histograms, loss ----------------
__global__ __launch_bounds__(128) void k_fin(const float* __restrict__ pmin, const int* __restrict__ pidx,
                                             int* __restrict__ idx,
                                             int* __restrict__ counts, int* __restrict__ countb,
                                             double* __restrict__ loss_sum){
    int n = blockIdx.x*128 + threadIdx.x;
    float v0 = pmin[n*2], v1 = pmin[n*2+1];
    int   i0 = pidx[n*2], i1 = pidx[n*2+1];
    float bv = v0; int bix = i0;
    if(v1 < bv){ bv = v1; bix = i1; }
    idx[n] = bix;
    atomicAdd(&counts[bix], 1);
    int b = n / (NCq*NCq);
    atomicAdd(&countb[b*NE + bix], 1);
    float md = bv;
    #pragma unroll
    for(int m=32;m;m>>=1) md += __shfl_xor(md, m, 64);
    __shared__ float red[2];
    if((threadIdx.x&63)==0) red[threadIdx.x>>6] = md;
    __syncthreads();
    if(threadIdx.x==0) atomicAdd(loss_sum, (double)(red[0]+red[1]));
}

// ---------------- scalars: vq_loss and usage ----------------
__global__ __launch_bounds__(256) void k_scal(const int* __restrict__ counts, const double* __restrict__ loss_sum,
                                              float* __restrict__ out){
    int t = threadIdx.x;
    float ent = 0.f;
    for(int e=t; e<NE; e+=256){
        float pr = (float)counts[e] / (float)NZ;
        ent += pr * logf(pr + 1e-10f);
    }
    #pragma unroll
    for(int m=32;m;m>>=1) ent += __shfl_xor(ent,m,64);
    __shared__ float red[4];
    if((t&63)==0) red[t>>6]=ent;
    __syncthreads();
    if(t==0){
        float e2 = red[0]+red[1]+red[2]+red[3];
        out[1+NZ] = expf(-e2);
        out[0] = (float)(1.25 * (*loss_sum) / ((double)NZ * (double)F_));
    }
}

// ---------------- SE block: s2p1 = 1 + sigmoid(MLP(mean)) per (b,d) ----------------
__global__ __launch_bounds__(256) void k_se(const int* __restrict__ countb, const float* __restrict__ cb,
                                            const float* __restrict__ w1, const float* __restrict__ b1,
                                            const float* __restrict__ w2, const float* __restrict__ b2,
                                            float* __restrict__ s2p1){
    int b = blockIdx.x; int d = threadIdx.x;
    __shared__ float cnt[NE];
    __shared__ float s_sh[F_];
    __shared__ float h_sh[16];
    cnt[d]       = (float)countb[b*NE + d];
    cnt[d + 256] = (float)countb[b*NE + d + 256];
    __syncthreads();
    float s = 0.f;
    for(int e=0;e<NE;e++) s = fmaf(cnt[e], cb[e*F_ + d], s);
    s *= (1.0f/(float)(NCq*NCq));
    s_sh[d] = s;
    __syncthreads();
    if(d < 16){
        float h = b1[d];
        for(int k=0;k<F_;k++) h = fmaf(s_sh[k], w1[k*16 + d], h);
        h_sh[d] = fmaxf(h, 0.f);
    }
    __syncthreads();
    float v = b2[d];
    #pragma unroll
    for(int r=0;r<16;r++) v = fmaf(h_sh[r], w2[r*F_ + d], v);
    s2p1[b*F_ + d] = 1.0f + 1.0f/(1.0f + expf(-v));
}

// ---------------- w[b,e] = sum_d elu(c[e,d]*(1+s2[b,d])) ----------------
__global__ __launch_bounds__(256) void k_w(const float* __restrict__ cb, const float* __restrict__ s2p1,
                                           float* __restrict__ wtab){
    int b = blockIdx.x; int eg = blockIdx.y;
    int wv = threadIdx.x>>6, lane = threadIdx.x&63;
    __shared__ float m_sh[F_];
    m_sh[threadIdx.x] = s2p1[b*F_ + threadIdx.x];
    __syncthreads();
    int e = eg*4 + wv;
    float4 c4 = *(const float4*)&cb[e*F_ + lane*4];
    float s = eluf(c4.x*m_sh[lane*4]) + eluf(c4.y*m_sh[lane*4+1])
            + eluf(c4.z*m_sh[lane*4+2]) + eluf(c4.w*m_sh[lane*4+3]);
    #pragma unroll
    for(int m2=32;m2;m2>>=1) s += __shfl_xor(s,m2,64);
    if(lane==0) wtab[b*NE + e] = s;
}

// ---------------- final: out[b,i,j] = normalize_j(elu(w[b, idx])) ----------------
__global__ __launch_bounds__(64) void k_out(const int* __restrict__ idx, const float* __restrict__ wtab,
                                            float* __restrict__ out){
    int bi = blockIdx.x; int j = threadIdx.x;
    int b = bi / NCq;
    float v = 0.f;
    if(j < NCq) v = eluf(wtab[b*NE + idx[bi*NCq + j]]);
    float a = fabsf(v);
    #pragma unroll
    for(int m=32;m;m>>=1) a += __shfl_xor(a,m,64);
    if(j < NCq) out[1 + bi*NCq + j] = v / (a + EPSF);
}

extern "C" void kernel_launch(void* const* d_in, const int* in_sizes, int n_in,
                              void* d_out, int out_size, void* d_ws, size_t ws_size,
                              hipStream_t stream){
    (void)in_sizes; (void)n_in; (void)out_size; (void)ws_size;
    const float* x    = (const float*)d_in[0];
    const float* p    = (const float*)d_in[1];
    const float* bias = (const float*)d_in[2];
    const float* q    = (const float*)d_in[3];
    const float* th   = (const float*)d_in[4];
    const float* cb   = (const float*)d_in[5];
    const float* w1   = (const float*)d_in[6];
    const float* b1   = (const float*)d_in[7];
    const float* w2   = (const float*)d_in[8];
    const float* b2   = (const float*)d_in[9];
    float* out = (float*)d_out;
    char* ws = (char*)d_ws;
    size_t off = 0;
    auto alloc = [&](size_t bytes){ void* ptr = ws + off; off = (off + bytes + 255) & ~255ull; return ptr; };
    float*    G    = (float*)   alloc((size_t)M_*NCOL*sizeof(float));      // 126 MB
    ushort_t* THh  = (ushort_t*)alloc((size_t)F_*NCOL*sizeof(ushort_t));   // 8.1 MB (transposed [n][k])
    ushort_t* THl  = (ushort_t*)alloc((size_t)F_*NCOL*sizeof(ushort_t));   // 8.1 MB
    ushort_t* Th   = (ushort_t*)alloc((size_t)M_*F_*sizeof(ushort_t));
    ushort_t* Tl   = (ushort_t*)alloc((size_t)M_*F_*sizeof(ushort_t));
    ushort_t* CBh  = (ushort_t*)alloc((size_t)NE*F_*sizeof(ushort_t));
    ushort_t* CBl  = (ushort_t*)alloc((size_t)NE*F_*sizeof(ushort_t));
    float*    INV  = (float*)   alloc((size_t)M_*F_*sizeof(float));
    float*    CN   = (float*)   alloc((size_t)NE*sizeof(float));
    float*    PMIN = (float*)   alloc((size_t)NZ*2*sizeof(float));
    int*      PIDX = (int*)     alloc((size_t)NZ*2*sizeof(int));
    int*      IDX  = (int*)     alloc((size_t)NZ*sizeof(int));
    char*     zbase= (char*)    alloc(8 + NE*sizeof(int) + (size_t)B_*NE*sizeof(int));
    double*   LOSS   = (double*)zbase;
    int*      COUNTS = (int*)(zbase + 8);
    int*      COUNTB = (int*)(zbase + 8 + NE*sizeof(int));
    float*    S2P1 = (float*)alloc((size_t)B_*F_*sizeof(float));
    float*    WTAB = (float*)alloc((size_t)B_*NE*sizeof(float));

    (void)hipMemsetAsync(zbase, 0, 8 + NE*sizeof(int) + (size_t)B_*NE*sizeof(int), stream);
    dim3 gth(NCOL/32, F_/32);
    k_split_th<<<gth, 256, 0, stream>>>(th, THh, THl);
    k_prep<<<NE, 256, 0, stream>>>(cb, CBh, CBl, CN, out + 1 + NZ + 1);
    k_ot<<<M_, 256, 0, stream>>>(x, p, bias, q, Th, Tl);
    dim3 g3(M_/64, NCOL/128);
    k_gemm_g<<<g3, 256, 0, stream>>>(Th, Tl, THh, THl, G);
    k_den<<<M_, 256, 0, stream>>>(G, INV, LOSS);
    dim3 g5(NZ/128, 2);
    k_vq<<<g5, 256, 0, stream>>>(G, INV, CBh, CBl, CN, PMIN, PIDX);
    k_fin<<<NZ/128, 128, 0, stream>>>(PMIN, PIDX, IDX, COUNTS, COUNTB, LOSS);
    k_scal<<<1, 256, 0, stream>>>(COUNTS, LOSS, out);
    k_se<<<B_, 256, 0, stream>>>(COUNTB, cb, w1, b1, w2, b2, S2P1);
    dim3 g8(B_, NE/4);
    k_w<<<g8, 256, 0, stream>>>(cb, S2P1, WTAB);
    k_out<<<M_, 64, 0, stream>>>(IDX, WTAB, out);
}

// Round 5
// 571.185 us; speedup vs baseline: 1.7974x; 1.0786x over previous
//
#include <hip/hip_runtime.h>
#include <math.h>

#define B_   32
#define NCq  62
#define F_   256
#define NE   512
#define M_   (B_*NCq)      // 1984
#define NCOL (NCq*F_)      // 15872
#define NZ   (M_*NCq)      // 123008
#define EPSF 1e-6f

typedef unsigned short ushort_t;
typedef unsigned int uint_t;
typedef __bf16 bf8_t __attribute__((ext_vector_type(8)));
typedef float f4_t __attribute__((ext_vector_type(4)));
typedef ushort_t us8_t __attribute__((ext_vector_type(8)));

__device__ __forceinline__ float eluf(float x){ return x > 0.0f ? x : expm1f(x); }

__device__ __forceinline__ ushort_t bf16_rne(float f){
    uint_t u = __float_as_uint(f);
    uint_t r = (u + 0x7FFFu + ((u >> 16) & 1u)) >> 16;
    return (ushort_t)r;
}
__device__ __forceinline__ float bf16_f(ushort_t h){ return __uint_as_float(((uint_t)h) << 16); }
// returns lo<<16 | hi packed
__device__ __forceinline__ uint_t split2p(float f){
    ushort_t h = bf16_rne(f);
    ushort_t l = bf16_rne(f - bf16_f(h));
    return ((uint_t)l << 16) | (uint_t)h;
}
// XOR-swizzled LDS offset: row stride 32 ushorts (64B), 4 pieces of 8 ushorts (16B)
__device__ __forceinline__ int sw_off(int row, int piece){
    return row*32 + ((piece ^ ((row>>1)&3))*8);
}

// ---------------- split theta, transposed: THt[n][k] = TH[k][n] ----------------
__global__ __launch_bounds__(256) void k_split_th(const float* __restrict__ TH,
                                                  ushort_t* __restrict__ THh, ushort_t* __restrict__ THl){
    __shared__ float tile[32][33];
    int n0 = blockIdx.x * 32, k0 = blockIdx.y * 32;
    int tid = threadIdx.x;
    int cc = tid & 31, rr = tid >> 5;
    #pragma unroll
    for(int p=0;p<4;p++){
        int kk = rr + p*8;
        tile[kk][cc] = TH[(size_t)(k0+kk)*NCOL + n0 + cc];
    }
    __syncthreads();
    #pragma unroll
    for(int p=0;p<4;p++){
        int nn = rr + p*8;
        uint_t pk = split2p(tile[cc][nn]);
        size_t o = (size_t)(n0+nn)*F_ + k0 + cc;
        THh[o] = (ushort_t)(pk & 0xFFFFu);
        THl[o] = (ushort_t)(pk >> 16);
    }
}

// ---------------- codebook: split hi/lo, norms, output copy ----------------
__global__ __launch_bounds__(256) void k_prep(const float* __restrict__ cb,
                                              ushort_t* __restrict__ CBh, ushort_t* __restrict__ CBl,
                                              float* __restrict__ cnorm, float* __restrict__ out_cb){
    int e = blockIdx.x; int d = threadIdx.x;
    float v = cb[e*F_ + d];
    out_cb[e*F_ + d] = v;
    uint_t pk = split2p(v);
    CBh[e*F_ + d] = (ushort_t)(pk & 0xFFFFu);
    CBl[e*F_ + d] = (ushort_t)(pk >> 16);
    float s = v*v;
    #pragma unroll
    for(int m=32;m;m>>=1) s += __shfl_xor(s, m, 64);
    __shared__ float red[4];
    if((threadIdx.x & 63)==0) red[threadIdx.x>>6] = s;
    __syncthreads();
    if(threadIdx.x==0) cnorm[e] = red[0]+red[1]+red[2]+red[3];
}

// ---------------- o = p@x+bias; t = o@q; write split t ----------------
__global__ __launch_bounds__(256) void k_ot(const float* __restrict__ x, const float* __restrict__ p,
                                            const float* __restrict__ bias, const float* __restrict__ q,
                                            ushort_t* __restrict__ Th, ushort_t* __restrict__ Tl){
    int bi = blockIdx.x; int d = threadIdx.x;
    int b = bi / NCq, i = bi % NCq;
    __shared__ float pr[NCq];
    __shared__ float orow[F_];
    if(d < NCq) pr[d] = p[i*NCq + d];
    __syncthreads();
    float acc = bias[i*F_ + d];
    const float* xb = x + (size_t)b*NCq*F_ + d;
    #pragma unroll 2
    for(int j=0;j<NCq;j++) acc = fmaf(pr[j], xb[j*F_], acc);
    orow[d] = acc;
    __syncthreads();
    float t = 0.f;
    #pragma unroll 4
    for(int k=0;k<F_;k++) t = fmaf(orow[k], q[k*F_ + d], t);
    uint_t pk = split2p(t);
    Th[bi*F_ + d] = (ushort_t)(pk & 0xFFFFu);
    Tl[bi*F_ + d] = (ushort_t)(pk >> 16);
}

// ---------------- G = ELU(T @ theta), stored as split bf16 hi/lo ----------------
// block 128m x 256n, K-chunk 32; 4 waves in 2x2, wave tile 64x128
__global__ __launch_bounds__(256,2) void k_gemm_g(const ushort_t* __restrict__ Th, const ushort_t* __restrict__ Tl,
                                                  const ushort_t* __restrict__ Bht, const ushort_t* __restrict__ Blt,
                                                  ushort_t* __restrict__ Gh, ushort_t* __restrict__ Gl){
    __shared__ ushort_t Ah[128*32], Al[128*32], Bh[256*32], Bl[256*32];  // 48 KB
    int tid = threadIdx.x;
    int l = tid & 63, w = tid >> 6;
    int wr = w >> 1, wc = w & 1;
    int m = l & 15, quad = l >> 4;
    int row0 = blockIdx.x * 128, col0 = blockIdx.y * 256;
    f4_t acc[4][8] = {};
    for(int kc=0; kc<F_; kc+=32){
        #pragma unroll
        for(int p2=0;p2<2;p2++){
            int idx = tid + p2*256;
            int row = idx >> 2, piece = idx & 3;
            int rclamp = row0 + row; if(rclamp >= M_) rclamp = M_-1;
            size_t go = (size_t)rclamp*F_ + kc + piece*8;
            int lo_ = sw_off(row, piece);
            *(us8_t*)&Ah[lo_] = *(const us8_t*)&Th[go];
            *(us8_t*)&Al[lo_] = *(const us8_t*)&Tl[go];
        }
        #pragma unroll
        for(int p2=0;p2<4;p2++){
            int idx = tid + p2*256;
            int row = idx >> 2, piece = idx & 3;
            size_t go = (size_t)(col0 + row)*F_ + kc + piece*8;
            int lo_ = sw_off(row, piece);
            *(us8_t*)&Bh[lo_] = *(const us8_t*)&Bht[go];
            *(us8_t*)&Bl[lo_] = *(const us8_t*)&Blt[go];
        }
        __syncthreads();
        bf8_t a_h[4], a_l[4];
        #pragma unroll
        for(int mt=0;mt<4;mt++){
            int row = wr*64 + mt*16 + m;
            int off = sw_off(row, quad);
            a_h[mt] = *(const bf8_t*)&Ah[off];
            a_l[mt] = *(const bf8_t*)&Al[off];
        }
        #pragma unroll
        for(int nt=0;nt<8;nt++){
            int col = wc*128 + nt*16 + m;
            int off = sw_off(col, quad);
            bf8_t b_h = *(const bf8_t*)&Bh[off];
            bf8_t b_l = *(const bf8_t*)&Bl[off];
            #pragma unroll
            for(int mt=0;mt<4;mt++){
                acc[mt][nt] = __builtin_amdgcn_mfma_f32_16x16x32_bf16(a_h[mt], b_h, acc[mt][nt], 0,0,0);
                acc[mt][nt] = __builtin_amdgcn_mfma_f32_16x16x32_bf16(a_h[mt], b_l, acc[mt][nt], 0,0,0);
                acc[mt][nt] = __builtin_amdgcn_mfma_f32_16x16x32_bf16(a_l[mt], b_h, acc[mt][nt], 0,0,0);
            }
        }
        __syncthreads();
    }
    #pragma unroll
    for(int mt=0;mt<4;mt++){
        #pragma unroll
        for(int nt=0;nt<8;nt++){
            int rowb = row0 + wr*64 + mt*16 + quad*4;
            int colb = col0 + wc*128 + nt*16 + m;
            #pragma unroll
            for(int r=0;r<4;r++){
                int row = rowb + r;
                if(row < M_){
                    uint_t pk = split2p(eluf(acc[mt][nt][r]));
                    size_t o = (size_t)row*NCOL + colb;
                    Gh[o] = (ushort_t)(pk & 0xFFFFu);
                    Gl[o] = (ushort_t)(pk >> 16);
                }
            }
        }
    }
}

// ---------------- den + loss; renormalize Gh/Gl IN PLACE to split z ----------------
__global__ __launch_bounds__(256) void k_den(ushort_t* __restrict__ Gh, ushort_t* __restrict__ Gl,
                                             double* __restrict__ loss_sum){
    int bi = blockIdx.x; int d = threadIdx.x;
    size_t base = (size_t)bi*NCOL + d;
    float v[NCq];
    float s1 = 0.f, s2 = 0.f;
    #pragma unroll
    for(int j=0;j<NCq;j++){
        size_t o = base + (size_t)j*F_;
        float t = bf16_f(Gh[o]) + bf16_f(Gl[o]);
        v[j] = t;
        s1 += fabsf(t);
        s2 = fmaf(t, t, s2);
    }
    float inv = 1.0f / (s1 + EPSF);
    #pragma unroll
    for(int j=0;j<NCq;j++){
        uint_t pk = split2p(v[j]*inv);
        size_t o = base + (size_t)j*F_;
        Gh[o] = (ushort_t)(pk & 0xFFFFu);
        Gl[o] = (ushort_t)(pk >> 16);
    }
    float c = s2 * inv * inv;
    #pragma unroll
    for(int m=32;m;m>>=1) c += __shfl_xor(c, m, 64);
    __shared__ float red[4];
    if((threadIdx.x&63)==0) red[threadIdx.x>>6] = c;
    __syncthreads();
    if(threadIdx.x==0) atomicAdd(loss_sum, (double)(red[0]+red[1]+red[2]+red[3]));
}

// ---------------- VQ: dist GEMM (split-bf16 MFMA) + per-quarter argmin ----------------
// block 128 rows x 256 codes; 4 waves 2x2, wave tile 64x128
__global__ __launch_bounds__(256,2) void k_vq(const ushort_t* __restrict__ Zh, const ushort_t* __restrict__ Zl,
                                              const ushort_t* __restrict__ CBh, const ushort_t* __restrict__ CBl,
                                              const float* __restrict__ cnorm,
                                              float* __restrict__ pmin, int* __restrict__ pidx){
    __shared__ ushort_t Ah[128*32], Al[128*32], Bh[256*32], Bl[256*32];  // 48 KB
    int tid = threadIdx.x;
    int l = tid & 63, w = tid >> 6;
    int wr = w >> 1, wc = w & 1;
    int m = l & 15, quad = l >> 4;
    int n_base = blockIdx.x * 128;
    int e0 = blockIdx.y * 256;
    f4_t acc[4][8] = {};
    for(int kc=0; kc<F_; kc+=32){
        #pragma unroll
        for(int p2=0;p2<2;p2++){
            int idx = tid + p2*256;
            int row = idx >> 2, piece = idx & 3;
            size_t go = (size_t)(n_base + row)*F_ + kc + piece*8;
            int lo_ = sw_off(row, piece);
            *(us8_t*)&Ah[lo_] = *(const us8_t*)&Zh[go];
            *(us8_t*)&Al[lo_] = *(const us8_t*)&Zl[go];
        }
        #pragma unroll
        for(int p2=0;p2<4;p2++){
            int idx = tid + p2*256;
            int row = idx >> 2, piece = idx & 3;
            size_t go = (size_t)(e0 + row)*F_ + kc + piece*8;
            int lo_ = sw_off(row, piece);
            *(us8_t*)&Bh[lo_] = *(const us8_t*)&CBh[go];
            *(us8_t*)&Bl[lo_] = *(const us8_t*)&CBl[go];
        }
        __syncthreads();
        bf8_t a_h[4], a_l[4];
        #pragma unroll
        for(int mt=0;mt<4;mt++){
            int row = wr*64 + mt*16 + m;
            int off = sw_off(row, quad);
            a_h[mt] = *(const bf8_t*)&Ah[off];
            a_l[mt] = *(const bf8_t*)&Al[off];
        }
        #pragma unroll
        for(int nt=0;nt<8;nt++){
            int col = wc*128 + nt*16 + m;
            int off = sw_off(col, quad);
            bf8_t b_h = *(const bf8_t*)&Bh[off];
            bf8_t b_l = *(const bf8_t*)&Bl[off];
            #pragma unroll
            for(int mt=0;mt<4;mt++){
                acc[mt][nt] = __builtin_amdgcn_mfma_f32_16x16x32_bf16(a_h[mt], b_h, acc[mt][nt], 0,0,0);
                acc[mt][nt] = __builtin_amdgcn_mfma_f32_16x16x32_bf16(a_h[mt], b_l, acc[mt][nt], 0,0,0);
                acc[mt][nt] = __builtin_amdgcn_mfma_f32_16x16x32_bf16(a_l[mt], b_h, acc[mt][nt], 0,0,0);
            }
        }
        __syncthreads();
    }
    // epilogue: score = cnorm - 2*dot; argmin over the 128 codes this wave owns
    #pragma unroll
    for(int mt=0;mt<4;mt++){
        float bv[4]; int bix[4];
        #pragma unroll
        for(int r=0;r<4;r++){ bv[r] = 3.4e38f; bix[r] = 0; }
        #pragma unroll
        for(int nt=0;nt<8;nt++){
            int e = e0 + wc*128 + nt*16 + m;
            float cn = cnorm[e];
            #pragma unroll
            for(int r=0;r<4;r++){
                float vv = cn - 2.0f*acc[mt][nt][r];
                if(vv < bv[r]){ bv[r] = vv; bix[r] = e; }
            }
        }
        #pragma unroll
        for(int r=0;r<4;r++){
            float vv = bv[r]; int ix = bix[r];
            #pragma unroll
            for(int mk=8;mk;mk>>=1){
                float ov = __shfl_xor(vv, mk, 64);
                int   oi = __shfl_xor(ix, mk, 64);
                if(ov < vv || (ov == vv && oi < ix)){ vv = ov; ix = oi; }
            }
            if(m == 0){
                int n = n_base + wr*64 + mt*16 + quad*4 + r;
                int slot = blockIdx.y*2 + wc;   // ascending code ranges
                pmin[n*4 + slot] = vv;
                pidx[n*4 + slot] = ix;
            }
        }
    }
}

// ---------------- finalize: min over 4 slots, histograms, loss ----------------
__global__ __launch_bounds__(128) void k_fin(const float* __restrict__ pmin, const int* __restrict__ pidx,
                                             int* __restrict__ idx,
                                             int* __restrict__ counts, int* __restrict__ countb,
                                             double* __restrict__ loss_sum){
    int n = blockIdx.x*128 + threadIdx.x;
    float bv = pmin[n*4]; int bix = pidx[n*4];
    #pragma unroll
    for(int c=1;c<4;c++){
        float v = pmin[n*4+c]; int i2 = pidx[n*4+c];
        if(v < bv || (v==bv && i2<bix)){ bv=v; bix=i2; }
    }
    idx[n] = bix;
    atomicAdd(&counts[bix], 1);
    int b = n / (NCq*NCq);
    atomicAdd(&countb[b*NE + bix], 1);
    float md = bv;
    #pragma unroll
    for(int m=32;m;m>>=1) md += __shfl_xor(md, m, 64);
    __shared__ float red[2];
    if((threadIdx.x&63)==0) red[threadIdx.x>>6] = md;
    __syncthreads();
    if(threadIdx.x==0) atomicAdd(loss_sum, (double)(red[0]+red[1]));
}

// ---------------- scalars: vq_loss and usage ----------------
__global__ __launch_bounds__(256) void k_scal(const int* __restrict__ counts, const double* __restrict__ loss_sum,
                                              float* __restrict__ out){
    int t = threadIdx.x;
    float ent = 0.f;
    for(int e=t; e<NE; e+=256){
        float pr = (float)counts[e] / (float)NZ;
        ent += pr * logf(pr + 1e-10f);
    }
    #pragma unroll
    for(int m=32;m;m>>=1) ent += __shfl_xor(ent,m,64);
    __shared__ float red[4];
    if((t&63)==0) red[t>>6]=ent;
    __syncthreads();
    if(t==0){
        float e2 = red[0]+red[1]+red[2]+red[3];
        out[1+NZ] = expf(-e2);
        out[0] = (float)(1.25 * (*loss_sum) / ((double)NZ * (double)F_));
    }
}

// ---------------- SE block: s2p1 = 1 + sigmoid(MLP(mean)) per (b,d) ----------------
__global__ __launch_bounds__(256) void k_se(const int* __restrict__ countb, const float* __restrict__ cb,
                                            const float* __restrict__ w1, const float* __restrict__ b1,
                                            const float* __restrict__ w2, const float* __restrict__ b2,
                                            float* __restrict__ s2p1){
    int b = blockIdx.x; int d = threadIdx.x;
    __shared__ float cnt[NE];
    __shared__ float s_sh[F_];
    __shared__ float h_sh[16];
    cnt[d]       = (float)countb[b*NE + d];
    cnt[d + 256] = (float)countb[b*NE + d + 256];
    __syncthreads();
    float s = 0.f;
    for(int e=0;e<NE;e++) s = fmaf(cnt[e], cb[e*F_ + d], s);
    s *= (1.0f/(float)(NCq*NCq));
    s_sh[d] = s;
    __syncthreads();
    if(d < 16){
        float h = b1[d];
        for(int k=0;k<F_;k++) h = fmaf(s_sh[k], w1[k*16 + d], h);
        h_sh[d] = fmaxf(h, 0.f);
    }
    __syncthreads();
    float v = b2[d];
    #pragma unroll
    for(int r=0;r<16;r++) v = fmaf(h_sh[r], w2[r*F_ + d], v);
    s2p1[b*F_ + d] = 1.0f + 1.0f/(1.0f + expf(-v));
}

// ---------------- w[b,e] = sum_d elu(c[e,d]*(1+s2[b,d])) ----------------
__global__ __launch_bounds__(256) void k_w(const float* __restrict__ cb, const float* __restrict__ s2p1,
                                           float* __restrict__ wtab){
    int b = blockIdx.x; int eg = blockIdx.y;
    int wv = threadIdx.x>>6, lane = threadIdx.x&63;
    __shared__ float m_sh[F_];
    m_sh[threadIdx.x] = s2p1[b*F_ + threadIdx.x];
    __syncthreads();
    int e = eg*4 + wv;
    float4 c4 = *(const float4*)&cb[e*F_ + lane*4];
    float s = eluf(c4.x*m_sh[lane*4]) + eluf(c4.y*m_sh[lane*4+1])
            + eluf(c4.z*m_sh[lane*4+2]) + eluf(c4.w*m_sh[lane*4+3]);
    #pragma unroll
    for(int m2=32;m2;m2>>=1) s += __shfl_xor(s,m2,64);
    if(lane==0) wtab[b*NE + e] = s;
}

// ---------------- final: out[b,i,j] = normalize_j(elu(w[b, idx])) ----------------
__global__ __launch_bounds__(64) void k_out(const int* __restrict__ idx, const float* __restrict__ wtab,
                                            float* __restrict__ out){
    int bi = blockIdx.x; int j = threadIdx.x;
    int b = bi / NCq;
    float v = 0.f;
    if(j < NCq) v = eluf(wtab[b*NE + idx[bi*NCq + j]]);
    float a = fabsf(v);
    #pragma unroll
    for(int m=32;m;m>>=1) a += __shfl_xor(a,m,64);
    if(j < NCq) out[1 + bi*NCq + j] = v / (a + EPSF);
}

extern "C" void kernel_launch(void* const* d_in, const int* in_sizes, int n_in,
                              void* d_out, int out_size, void* d_ws, size_t ws_size,
                              hipStream_t stream){
    (void)in_sizes; (void)n_in; (void)out_size; (void)ws_size;
    const float* x    = (const float*)d_in[0];
    const float* p    = (const float*)d_in[1];
    const float* bias = (const float*)d_in[2];
    const float* q    = (const float*)d_in[3];
    const float* th   = (const float*)d_in[4];
    const float* cb   = (const float*)d_in[5];
    const float* w1   = (const float*)d_in[6];
    const float* b1   = (const float*)d_in[7];
    const float* w2   = (const float*)d_in[8];
    const float* b2   = (const float*)d_in[9];
    float* out = (float*)d_out;
    char* ws = (char*)d_ws;
    size_t off = 0;
    auto alloc = [&](size_t bytes){ void* ptr = ws + off; off = (off + bytes + 255) & ~255ull; return ptr; };
    ushort_t* Gh   = (ushort_t*)alloc((size_t)NZ*F_*sizeof(ushort_t));      // 60 MiB (doubles as Zh)
    ushort_t* Gl   = (ushort_t*)alloc((size_t)NZ*F_*sizeof(ushort_t));      // 60 MiB (doubles as Zl)
    ushort_t* THh  = (ushort_t*)alloc((size_t)F_*NCOL*sizeof(ushort_t));    // 7.75 MiB ([n][k])
    ushort_t* THl  = (ushort_t*)alloc((size_t)F_*NCOL*sizeof(ushort_t));
    ushort_t* Th   = (ushort_t*)alloc((size_t)M_*F_*sizeof(ushort_t));
    ushort_t* Tl   = (ushort_t*)alloc((size_t)M_*F_*sizeof(ushort_t));
    ushort_t* CBh  = (ushort_t*)alloc((size_t)NE*F_*sizeof(ushort_t));
    ushort_t* CBl  = (ushort_t*)alloc((size_t)NE*F_*sizeof(ushort_t));
    float*    CN   = (float*)   alloc((size_t)NE*sizeof(float));
    float*    PMIN = (float*)   alloc((size_t)NZ*4*sizeof(float));
    int*      PIDX = (int*)     alloc((size_t)NZ*4*sizeof(int));
    int*      IDX  = (int*)     alloc((size_t)NZ*sizeof(int));
    char*     zbase= (char*)    alloc(8 + NE*sizeof(int) + (size_t)B_*NE*sizeof(int));
    double*   LOSS   = (double*)zbase;
    int*      COUNTS = (int*)(zbase + 8);
    int*      COUNTB = (int*)(zbase + 8 + NE*sizeof(int));
    float*    S2P1 = (float*)alloc((size_t)B_*F_*sizeof(float));
    float*    WTAB = (float*)alloc((size_t)B_*NE*sizeof(float));

    (void)hipMemsetAsync(zbase, 0, 8 + NE*sizeof(int) + (size_t)B_*NE*sizeof(int), stream);
    dim3 gth(NCOL/32, F_/32);
    k_split_th<<<gth, 256, 0, stream>>>(th, THh, THl);
    k_prep<<<NE, 256, 0, stream>>>(cb, CBh, CBl, CN, out + 1 + NZ + 1);
    k_ot<<<M_, 256, 0, stream>>>(x, p, bias, q, Th, Tl);
    dim3 g3((M_ + 127)/128, NCOL/256);   // 16 x 62 (tail rows guarded)
    k_gemm_g<<<g3, 256, 0, stream>>>(Th, Tl, THh, THl, Gh, Gl);
    k_den<<<M_, 256, 0, stream>>>(Gh, Gl, LOSS);
    dim3 g5(NZ/128, 2);
    k_vq<<<g5, 256, 0, stream>>>(Gh, Gl, CBh, CBl, CN, PMIN, PIDX);
    k_fin<<<NZ/128, 128, 0, stream>>>(PMIN, PIDX, IDX, COUNTS, COUNTB, LOSS);
    k_scal<<<1, 256, 0, stream>>>(COUNTS, LOSS, out);
    k_se<<<B_, 256, 0, stream>>>(COUNTB, cb, w1, b1, w2, b2, S2P1);
    dim3 g8(B_, NE/4);
    k_w<<<g8, 256, 0, stream>>>(cb, S2P1, WTAB);
    k_out<<<M_, 64, 0, stream>>>(IDX, WTAB, out);
}

// Round 6
// 408.019 us; speedup vs baseline: 2.5162x; 1.3999x over previous
//
#include <hip/hip_runtime.h>
#include <math.h>

#define B_   32
#define NCq  62
#define F_   256
#define NE   512
#define M_   (B_*NCq)      // 1984
#define NCOL (NCq*F_)      // 15872
#define NZ   (M_*NCq)      // 123008
#define EPSF 1e-6f

typedef unsigned short ushort_t;
typedef unsigned int uint_t;
typedef __bf16 bf8_t __attribute__((ext_vector_type(8)));
typedef float f4_t __attribute__((ext_vector_type(4)));
typedef ushort_t us8_t __attribute__((ext_vector_type(8)));

__device__ __forceinline__ float eluf(float x){ return x > 0.0f ? x : expm1f(x); }

__device__ __forceinline__ ushort_t bf16_rne(float f){
    uint_t u = __float_as_uint(f);
    uint_t r = (u + 0x7FFFu + ((u >> 16) & 1u)) >> 16;
    return (ushort_t)r;
}
__device__ __forceinline__ float bf16_f(ushort_t h){ return __uint_as_float(((uint_t)h) << 16); }
// returns lo<<16 | hi packed
__device__ __forceinline__ uint_t split2p(float f){
    ushort_t h = bf16_rne(f);
    ushort_t l = bf16_rne(f - bf16_f(h));
    return ((uint_t)l << 16) | (uint_t)h;
}
// XOR-swizzled LDS offset: row stride 32 ushorts (64B), 4 pieces of 8 ushorts (16B)
__device__ __forceinline__ int sw_off(int row, int piece){
    return row*32 + ((piece ^ ((row>>1)&3))*8);
}

// ---------------- split theta, transposed: THt[n][k] = TH[k][n] ----------------
__global__ __launch_bounds__(256) void k_split_th(const float* __restrict__ TH,
                                                  ushort_t* __restrict__ THh, ushort_t* __restrict__ THl){
    __shared__ float tile[32][33];
    int n0 = blockIdx.x * 32, k0 = blockIdx.y * 32;
    int tid = threadIdx.x;
    int cc = tid & 31, rr = tid >> 5;
    #pragma unroll
    for(int p=0;p<4;p++){
        int kk = rr + p*8;
        tile[kk][cc] = TH[(size_t)(k0+kk)*NCOL + n0 + cc];
    }
    __syncthreads();
    #pragma unroll
    for(int p=0;p<4;p++){
        int nn = rr + p*8;
        uint_t pk = split2p(tile[cc][nn]);
        size_t o = (size_t)(n0+nn)*F_ + k0 + cc;
        THh[o] = (ushort_t)(pk & 0xFFFFu);
        THl[o] = (ushort_t)(pk >> 16);
    }
}

// ---------------- codebook: split hi/lo, norms, output copy ----------------
__global__ __launch_bounds__(256) void k_prep(const float* __restrict__ cb,
                                              ushort_t* __restrict__ CBh, ushort_t* __restrict__ CBl,
                                              float* __restrict__ cnorm, float* __restrict__ out_cb){
    int e = blockIdx.x; int d = threadIdx.x;
    float v = cb[e*F_ + d];
    out_cb[e*F_ + d] = v;
    uint_t pk = split2p(v);
    CBh[e*F_ + d] = (ushort_t)(pk & 0xFFFFu);
    CBl[e*F_ + d] = (ushort_t)(pk >> 16);
    float s = v*v;
    #pragma unroll
    for(int m=32;m;m>>=1) s += __shfl_xor(s, m, 64);
    __shared__ float red[4];
    if((threadIdx.x & 63)==0) red[threadIdx.x>>6] = s;
    __syncthreads();
    if(threadIdx.x==0) cnorm[e] = red[0]+red[1]+red[2]+red[3];
}

// ---------------- o = p@x+bias; t = o@q; write split t ----------------
__global__ __launch_bounds__(256) void k_ot(const float* __restrict__ x, const float* __restrict__ p,
                                            const float* __restrict__ bias, const float* __restrict__ q,
                                            ushort_t* __restrict__ Th, ushort_t* __restrict__ Tl){
    int bi = blockIdx.x; int d = threadIdx.x;
    int b = bi / NCq, i = bi % NCq;
    __shared__ float pr[NCq];
    __shared__ float orow[F_];
    if(d < NCq) pr[d] = p[i*NCq + d];
    __syncthreads();
    float acc = bias[i*F_ + d];
    const float* xb = x + (size_t)b*NCq*F_ + d;
    #pragma unroll 2
    for(int j=0;j<NCq;j++) acc = fmaf(pr[j], xb[j*F_], acc);
    orow[d] = acc;
    __syncthreads();
    float t = 0.f;
    #pragma unroll 4
    for(int k=0;k<F_;k++) t = fmaf(orow[k], q[k*F_ + d], t);
    uint_t pk = split2p(t);
    Th[bi*F_ + d] = (ushort_t)(pk & 0xFFFFu);
    Tl[bi*F_ + d] = (ushort_t)(pk >> 16);
}

// ---------------- G = ELU(T @ theta), stored as split bf16 hi/lo ----------------
// block 128m x 256n, K-chunk 32; 4 waves in 2x2, wave tile 64x128
__global__ __launch_bounds__(256,2) void k_gemm_g(const ushort_t* __restrict__ Th, const ushort_t* __restrict__ Tl,
                                                  const ushort_t* __restrict__ Bht, const ushort_t* __restrict__ Blt,
                                                  ushort_t* __restrict__ Gh, ushort_t* __restrict__ Gl){
    __shared__ ushort_t Ah[128*32], Al[128*32], Bh[256*32], Bl[256*32];  // 48 KB
    int tid = threadIdx.x;
    int l = tid & 63, w = tid >> 6;
    int wr = w >> 1, wc = w & 1;
    int m = l & 15, quad = l >> 4;
    int row0 = blockIdx.x * 128, col0 = blockIdx.y * 256;
    f4_t acc[4][8] = {};
    for(int kc=0; kc<F_; kc+=32){
        #pragma unroll
        for(int p2=0;p2<2;p2++){
            int idx = tid + p2*256;
            int row = idx >> 2, piece = idx & 3;
            int rclamp = row0 + row; if(rclamp >= M_) rclamp = M_-1;
            size_t go = (size_t)rclamp*F_ + kc + piece*8;
            int lo_ = sw_off(row, piece);
            *(us8_t*)&Ah[lo_] = *(const us8_t*)&Th[go];
            *(us8_t*)&Al[lo_] = *(const us8_t*)&Tl[go];
        }
        #pragma unroll
        for(int p2=0;p2<4;p2++){
            int idx = tid + p2*256;
            int row = idx >> 2, piece = idx & 3;
            size_t go = (size_t)(col0 + row)*F_ + kc + piece*8;
            int lo_ = sw_off(row, piece);
            *(us8_t*)&Bh[lo_] = *(const us8_t*)&Bht[go];
            *(us8_t*)&Bl[lo_] = *(const us8_t*)&Blt[go];
        }
        __syncthreads();
        bf8_t a_h[4], a_l[4];
        #pragma unroll
        for(int mt=0;mt<4;mt++){
            int row = wr*64 + mt*16 + m;
            int off = sw_off(row, quad);
            a_h[mt] = *(const bf8_t*)&Ah[off];
            a_l[mt] = *(const bf8_t*)&Al[off];
        }
        #pragma unroll
        for(int nt=0;nt<8;nt++){
            int col = wc*128 + nt*16 + m;
            int off = sw_off(col, quad);
            bf8_t b_h = *(const bf8_t*)&Bh[off];
            bf8_t b_l = *(const bf8_t*)&Bl[off];
            #pragma unroll
            for(int mt=0;mt<4;mt++){
                acc[mt][nt] = __builtin_amdgcn_mfma_f32_16x16x32_bf16(a_h[mt], b_h, acc[mt][nt], 0,0,0);
                acc[mt][nt] = __builtin_amdgcn_mfma_f32_16x16x32_bf16(a_h[mt], b_l, acc[mt][nt], 0,0,0);
                acc[mt][nt] = __builtin_amdgcn_mfma_f32_16x16x32_bf16(a_l[mt], b_h, acc[mt][nt], 0,0,0);
            }
        }
        __syncthreads();
    }
    #pragma unroll
    for(int mt=0;mt<4;mt++){
        #pragma unroll
        for(int nt=0;nt<8;nt++){
            int rowb = row0 + wr*64 + mt*16 + quad*4;
            int colb = col0 + wc*128 + nt*16 + m;
            #pragma unroll
            for(int r=0;r<4;r++){
                int row = rowb + r;
                if(row < M_){
                    uint_t pk = split2p(eluf(acc[mt][nt][r]));
                    size_t o = (size_t)row*NCOL + colb;
                    Gh[o] = (ushort_t)(pk & 0xFFFFu);
                    Gl[o] = (ushort_t)(pk >> 16);
                }
            }
        }
    }
}

// ---------------- den + loss; renormalize Gh/Gl IN PLACE to split z ----------------
__global__ __launch_bounds__(256) void k_den(ushort_t* __restrict__ Gh, ushort_t* __restrict__ Gl,
                                             double* __restrict__ loss_sum){
    int bi = blockIdx.x; int d = threadIdx.x;
    size_t base = (size_t)bi*NCOL + d;
    float v[NCq];
    float s1 = 0.f, s2 = 0.f;
    #pragma unroll
    for(int j=0;j<NCq;j++){
        size_t o = base + (size_t)j*F_;
        float t = bf16_f(Gh[o]) + bf16_f(Gl[o]);
        v[j] = t;
        s1 += fabsf(t);
        s2 = fmaf(t, t, s2);
    }
    float inv = 1.0f / (s1 + EPSF);
    #pragma unroll
    for(int j=0;j<NCq;j++){
        uint_t pk = split2p(v[j]*inv);
        size_t o = base + (size_t)j*F_;
        Gh[o] = (ushort_t)(pk & 0xFFFFu);
        Gl[o] = (ushort_t)(pk >> 16);
    }
    float c = s2 * inv * inv;
    #pragma unroll
    for(int m=32;m;m>>=1) c += __shfl_xor(c, m, 64);
    __shared__ float red[4];
    if((threadIdx.x&63)==0) red[threadIdx.x>>6] = c;
    __syncthreads();
    if(threadIdx.x==0) atomicAdd(loss_sum, (double)(red[0]+red[1]+red[2]+red[3]));
}

// ---------------- VQ: dist GEMM (split-bf16 MFMA) + per-quarter argmin ----------------
// block 128 rows x 256 codes; 4 waves 2x2, wave tile 64x128
__global__ __launch_bounds__(256,2) void k_vq(const ushort_t* __restrict__ Zh, const ushort_t* __restrict__ Zl,
                                              const ushort_t* __restrict__ CBh, const ushort_t* __restrict__ CBl,
                                              const float* __restrict__ cnorm,
                                              float* __restrict__ pmin, int* __restrict__ pidx){
    __shared__ ushort_t Ah[128*32], Al[128*32], Bh[256*32], Bl[256*32];  // 48 KB
    int tid = threadIdx.x;
    int l = tid & 63, w = tid >> 6;
    int wr = w >> 1, wc = w & 1;
    int m = l & 15, quad = l >> 4;
    int n_base = blockIdx.x * 128;
    int e0 = blockIdx.y * 256;
    f4_t acc[4][8] = {};
    for(int kc=0; kc<F_; kc+=32){
        #pragma unroll
        for(int p2=0;p2<2;p2++){
            int idx = tid + p2*256;
            int row = idx >> 2, piece = idx & 3;
            size_t go = (size_t)(n_base + row)*F_ + kc + piece*8;
            int lo_ = sw_off(row, piece);
            *(us8_t*)&Ah[lo_] = *(const us8_t*)&Zh[go];
            *(us8_t*)&Al[lo_] = *(const us8_t*)&Zl[go];
        }
        #pragma unroll
        for(int p2=0;p2<4;p2++){
            int idx = tid + p2*256;
            int row = idx >> 2, piece = idx & 3;
            size_t go = (size_t)(e0 + row)*F_ + kc + piece*8;
            int lo_ = sw_off(row, piece);
            *(us8_t*)&Bh[lo_] = *(const us8_t*)&CBh[go];
            *(us8_t*)&Bl[lo_] = *(const us8_t*)&CBl[go];
        }
        __syncthreads();
        bf8_t a_h[4], a_l[4];
        #pragma unroll
        for(int mt=0;mt<4;mt++){
            int row = wr*64 + mt*16 + m;
            int off = sw_off(row, quad);
            a_h[mt] = *(const bf8_t*)&Ah[off];
            a_l[mt] = *(const bf8_t*)&Al[off];
        }
        #pragma unroll
        for(int nt=0;nt<8;nt++){
            int col = wc*128 + nt*16 + m;
            int off = sw_off(col, quad);
            bf8_t b_h = *(const bf8_t*)&Bh[off];
            bf8_t b_l = *(const bf8_t*)&Bl[off];
            #pragma unroll
            for(int mt=0;mt<4;mt++){
                acc[mt][nt] = __builtin_amdgcn_mfma_f32_16x16x32_bf16(a_h[mt], b_h, acc[mt][nt], 0,0,0);
                acc[mt][nt] = __builtin_amdgcn_mfma_f32_16x16x32_bf16(a_h[mt], b_l, acc[mt][nt], 0,0,0);
                acc[mt][nt] = __builtin_amdgcn_mfma_f32_16x16x32_bf16(a_l[mt], b_h, acc[mt][nt], 0,0,0);
            }
        }
        __syncthreads();
    }
    // epilogue: score = cnorm - 2*dot; argmin over the 128 codes this wave owns
    #pragma unroll
    for(int mt=0;mt<4;mt++){
        float bv[4]; int bix[4];
        #pragma unroll
        for(int r=0;r<4;r++){ bv[r] = 3.4e38f; bix[r] = 0; }
        #pragma unroll
        for(int nt=0;nt<8;nt++){
            int e = e0 + wc*128 + nt*16 + m;
            float cn = cnorm[e];
            #pragma unroll
            for(int r=0;r<4;r++){
                float vv = cn - 2.0f*acc[mt][nt][r];
                if(vv < bv[r]){ bv[r] = vv; bix[r] = e; }
            }
        }
        #pragma unroll
        for(int r=0;r<4;r++){
            float vv = bv[r]; int ix = bix[r];
            #pragma unroll
            for(int mk=8;mk;mk>>=1){
                float ov = __shfl_xor(vv, mk, 64);
                int   oi = __shfl_xor(ix, mk, 64);
                if(ov < vv || (ov == vv && oi < ix)){ vv = ov; ix = oi; }
            }
            if(m == 0){
                int n = n_base + wr*64 + mt*16 + quad*4 + r;
                int slot = blockIdx.y*2 + wc;   // ascending code ranges
                pmin[n*4 + slot] = vv;
                pidx[n*4 + slot] = ix;
            }
        }
    }
}

// ---------------- finalize: one block per batch b; LDS histogram, no contended atomics ----------------
__global__ __launch_bounds__(1024) void k_fin(const float* __restrict__ pmin, const int* __restrict__ pidx,
                                              int* __restrict__ idx,
                                              int* __restrict__ counts, int* __restrict__ countb,
                                              double* __restrict__ loss_sum){
    int b = blockIdx.x;
    int t = threadIdx.x;
    __shared__ int hist[NE];
    __shared__ float red[16];
    #pragma unroll
    for(int e=t; e<NE; e+=1024) hist[e] = 0;
    __syncthreads();
    float msum = 0.f;
    int n0 = b * (NCq*NCq);
    for(int i=t; i<NCq*NCq; i+=1024){
        int n = n0 + i;
        float4 pv = *(const float4*)&pmin[n*4];
        int4   pi = *(const int4*)&pidx[n*4];
        float bv = pv.x; int bix = pi.x;
        if(pv.y < bv || (pv.y==bv && pi.y<bix)){ bv=pv.y; bix=pi.y; }
        if(pv.z < bv || (pv.z==bv && pi.z<bix)){ bv=pv.z; bix=pi.z; }
        if(pv.w < bv || (pv.w==bv && pi.w<bix)){ bv=pv.w; bix=pi.w; }
        idx[n] = bix;
        atomicAdd(&hist[bix], 1);
        msum += bv;
    }
    #pragma unroll
    for(int m=32;m;m>>=1) msum += __shfl_xor(msum, m, 64);
    if((t&63)==0) red[t>>6] = msum;
    __syncthreads();
    if(t==0){
        float s = 0.f;
        #pragma unroll
        for(int i2=0;i2<16;i2++) s += red[i2];
        atomicAdd(loss_sum, (double)s);
    }
    for(int e=t; e<NE; e+=1024){
        int c = hist[e];
        countb[b*NE + e] = c;            // exclusive per-b write
        if(c) atomicAdd(&counts[e], c);  // 512 atomics/block max
    }
}

// ---------------- scalars: vq_loss and usage ----------------
__global__ __launch_bounds__(256) void k_scal(const int* __restrict__ counts, const double* __restrict__ loss_sum,
                                              float* __restrict__ out){
    int t = threadIdx.x;
    float ent = 0.f;
    for(int e=t; e<NE; e+=256){
        float pr = (float)counts[e] / (float)NZ;
        ent += pr * logf(pr + 1e-10f);
    }
    #pragma unroll
    for(int m=32;m;m>>=1) ent += __shfl_xor(ent,m,64);
    __shared__ float red[4];
    if((t&63)==0) red[t>>6]=ent;
    __syncthreads();
    if(t==0){
        float e2 = red[0]+red[1]+red[2]+red[3];
        out[1+NZ] = expf(-e2);
        out[0] = (float)(1.25 * (*loss_sum) / ((double)NZ * (double)F_));
    }
}

// ---------------- SE block: s2p1 = 1 + sigmoid(MLP(mean)) per (b,d) ----------------
__global__ __launch_bounds__(256) void k_se(const int* __restrict__ countb, const float* __restrict__ cb,
                                            const float* __restrict__ w1, const float* __restrict__ b1,
                                            const float* __restrict__ w2, const float* __restrict__ b2,
                                            float* __restrict__ s2p1){
    int b = blockIdx.x; int d = threadIdx.x;
    __shared__ float cnt[NE];
    __shared__ float s_sh[F_];
    __shared__ float h_sh[16];
    cnt[d]       = (float)countb[b*NE + d];
    cnt[d + 256] = (float)countb[b*NE + d + 256];
    __syncthreads();
    float s = 0.f;
    for(int e=0;e<NE;e++) s = fmaf(cnt[e], cb[e*F_ + d], s);
    s *= (1.0f/(float)(NCq*NCq));
    s_sh[d] = s;
    __syncthreads();
    if(d < 16){
        float h = b1[d];
        for(int k=0;k<F_;k++) h = fmaf(s_sh[k], w1[k*16 + d], h);
        h_sh[d] = fmaxf(h, 0.f);
    }
    __syncthreads();
    float v = b2[d];
    #pragma unroll
    for(int r=0;r<16;r++) v = fmaf(h_sh[r], w2[r*F_ + d], v);
    s2p1[b*F_ + d] = 1.0f + 1.0f/(1.0f + expf(-v));
}

// ---------------- w[b,e] = sum_d elu(c[e,d]*(1+s2[b,d])) ----------------
__global__ __launch_bounds__(256) void k_w(const float* __restrict__ cb, const float* __restrict__ s2p1,
                                           float* __restrict__ wtab){
    int b = blockIdx.x; int eg = blockIdx.y;
    int wv = threadIdx.x>>6, lane = threadIdx.x&63;
    __shared__ float m_sh[F_];
    m_sh[threadIdx.x] = s2p1[b*F_ + threadIdx.x];
    __syncthreads();
    int e = eg*4 + wv;
    float4 c4 = *(const float4*)&cb[e*F_ + lane*4];
    float s = eluf(c4.x*m_sh[lane*4]) + eluf(c4.y*m_sh[lane*4+1])
            + eluf(c4.z*m_sh[lane*4+2]) + eluf(c4.w*m_sh[lane*4+3]);
    #pragma unroll
    for(int m2=32;m2;m2>>=1) s += __shfl_xor(s,m2,64);
    if(lane==0) wtab[b*NE + e] = s;
}

// ---------------- final: out[b,i,j] = normalize_j(elu(w[b, idx])) ----------------
__global__ __launch_bounds__(64) void k_out(const int* __restrict__ idx, const float* __restrict__ wtab,
                                            float* __restrict__ out){
    int bi = blockIdx.x; int j = threadIdx.x;
    int b = bi / NCq;
    float v = 0.f;
    if(j < NCq) v = eluf(wtab[b*NE + idx[bi*NCq + j]]);
    float a = fabsf(v);
    #pragma unroll
    for(int m=32;m;m>>=1) a += __shfl_xor(a,m,64);
    if(j < NCq) out[1 + bi*NCq + j] = v / (a + EPSF);
}

extern "C" void kernel_launch(void* const* d_in, const int* in_sizes, int n_in,
                              void* d_out, int out_size, void* d_ws, size_t ws_size,
                              hipStream_t stream){
    (void)in_sizes; (void)n_in; (void)out_size; (void)ws_size;
    const float* x    = (const float*)d_in[0];
    const float* p    = (const float*)d_in[1];
    const float* bias = (const float*)d_in[2];
    const float* q    = (const float*)d_in[3];
    const float* th   = (const float*)d_in[4];
    const float* cb   = (const float*)d_in[5];
    const float* w1   = (const float*)d_in[6];
    const float* b1   = (const float*)d_in[7];
    const float* w2   = (const float*)d_in[8];
    const float* b2   = (const float*)d_in[9];
    float* out = (float*)d_out;
    char* ws = (char*)d_ws;
    size_t off = 0;
    auto alloc = [&](size_t bytes){ void* ptr = ws + off; off = (off + bytes + 255) & ~255ull; return ptr; };
    ushort_t* Gh   = (ushort_t*)alloc((size_t)NZ*F_*sizeof(ushort_t));      // 60 MiB (doubles as Zh)
    ushort_t* Gl   = (ushort_t*)alloc((size_t)NZ*F_*sizeof(ushort_t));      // 60 MiB (doubles as Zl)
    ushort_t* THh  = (ushort_t*)alloc((size_t)F_*NCOL*sizeof(ushort_t));    // 7.75 MiB ([n][k])
    ushort_t* THl  = (ushort_t*)alloc((size_t)F_*NCOL*sizeof(ushort_t));
    ushort_t* Th   = (ushort_t*)alloc((size_t)M_*F_*sizeof(ushort_t));
    ushort_t* Tl   = (ushort_t*)alloc((size_t)M_*F_*sizeof(ushort_t));
    ushort_t* CBh  = (ushort_t*)alloc((size_t)NE*F_*sizeof(ushort_t));
    ushort_t* CBl  = (ushort_t*)alloc((size_t)NE*F_*sizeof(ushort_t));
    float*    CN   = (float*)   alloc((size_t)NE*sizeof(float));
    float*    PMIN = (float*)   alloc((size_t)NZ*4*sizeof(float));
    int*      PIDX = (int*)     alloc((size_t)NZ*4*sizeof(int));
    int*      IDX  = (int*)     alloc((size_t)NZ*sizeof(int));
    char*     zbase= (char*)    alloc(8 + NE*sizeof(int));
    double*   LOSS   = (double*)zbase;
    int*      COUNTS = (int*)(zbase + 8);
    int*      COUNTB = (int*)   alloc((size_t)B_*NE*sizeof(int));
    float*    S2P1 = (float*)alloc((size_t)B_*F_*sizeof(float));
    float*    WTAB = (float*)alloc((size_t)B_*NE*sizeof(float));

    (void)hipMemsetAsync(zbase, 0, 8 + NE*sizeof(int), stream);
    dim3 gth(NCOL/32, F_/32);
    k_split_th<<<gth, 256, 0, stream>>>(th, THh, THl);
    k_prep<<<NE, 256, 0, stream>>>(cb, CBh, CBl, CN, out + 1 + NZ + 1);
    k_ot<<<M_, 256, 0, stream>>>(x, p, bias, q, Th, Tl);
    dim3 g3((M_ + 127)/128, NCOL/256);   // 16 x 62 (tail rows guarded)
    k_gemm_g<<<g3, 256, 0, stream>>>(Th, Tl, THh, THl, Gh, Gl);
    k_den<<<M_, 256, 0, stream>>>(Gh, Gl, LOSS);
    dim3 g5(NZ/128, 2);
    k_vq<<<g5, 256, 0, stream>>>(Gh, Gl, CBh, CBl, CN, PMIN, PIDX);
    k_fin<<<B_, 1024, 0, stream>>>(PMIN, PIDX, IDX, COUNTS, COUNTB, LOSS);
    k_scal<<<1, 256, 0, stream>>>(COUNTS, LOSS, out);
    k_se<<<B_, 256, 0, stream>>>(COUNTB, cb, w1, b1, w2, b2, S2P1);
    dim3 g8(B_, NE/4);
    k_w<<<g8, 256, 0, stream>>>(cb, S2P1, WTAB);
    k_out<<<M_, 64, 0, stream>>>(IDX, WTAB, out);
}